// Round 12
// baseline (442.305 us; speedup 1.0000x reference)
//
#include <hip/hip_runtime.h>
#include <math.h>

typedef unsigned short ushort_t;
typedef unsigned int uint_t;
typedef unsigned long long ull_t;

__device__ __forceinline__ float bf2f(ushort_t u) {
    union { uint_t i; float f; } x; x.i = ((uint_t)u) << 16; return x.f;
}
__device__ __forceinline__ ushort_t f2bf(float f) {
    union { float f; uint_t i; } x; x.f = f;
    uint_t r = x.i + 0x7FFFu + ((x.i >> 16) & 1u);
    return (ushort_t)(r >> 16);
}

// ---------------- init: zero cnt/stats/wbias + prep layer-0 Wt ----------------
__global__ __launch_bounds__(256) void k_init(
    const float* __restrict__ W0, int* __restrict__ cnt, float* __restrict__ stats,
    float* __restrict__ wbias, ushort_t* __restrict__ Wt, int N)
{
    const int gt = blockIdx.x * 256 + threadIdx.x;
    const int gth = gridDim.x * 256;
    for (int i = gt; i < N; i += gth) cnt[i] = 0;
    for (int i = gt; i < 2048; i += gth) stats[i] = 0.f;
    if (gt < 256) wbias[gt] = 0.f;          // layer-0 wbias = 0
    // prep0: Wt[j][k] = bf16(W0[k][j]); K=256, M=220, Mp=224
    for (int idx = gt; idx < 224 * 256; idx += gth) {
        int j = idx >> 8;
        int k = idx & 255;
        float v = (j < 220) ? W0[(long)k * 220 + j] : 0.f;
        Wt[idx] = f2bf(v);
    }
}

// 4 edges per thread (E divisible by 4 here; tail guarded anyway)
__global__ void k_hist(const int* __restrict__ dst, int* __restrict__ cnt, int E) {
    int e4 = (blockIdx.x * blockDim.x + threadIdx.x) * 4;
    if (e4 + 3 < E) {
        int4 d = *(const int4*)(dst + e4);
        atomicAdd(&cnt[d.x], 1);
        atomicAdd(&cnt[d.y], 1);
        atomicAdd(&cnt[d.z], 1);
        atomicAdd(&cnt[d.w], 1);
    } else {
        for (int e = e4; e < E; ++e) atomicAdd(&cnt[dst[e]], 1);
    }
}

__global__ __launch_bounds__(1024) void k_scan(
    const int* __restrict__ cnt, int* __restrict__ row_start,
    int* __restrict__ cursor, float* __restrict__ dinv, int N)
{
    __shared__ int sh[1024];
    const int tid = threadIdx.x;
    const int chunk = (N + 1023) >> 10;
    int loc[16];
    const int base = tid * chunk;
    int sum = 0;
    for (int c = 0; c < chunk; ++c) {
        int i = base + c;
        int v = (i < N) ? cnt[i] : 0;
        loc[c] = sum;
        sum += v;
    }
    sh[tid] = sum;
    __syncthreads();
    for (int off = 1; off < 1024; off <<= 1) {
        int v = (tid >= off) ? sh[tid - off] : 0;
        __syncthreads();
        sh[tid] += v;
        __syncthreads();
    }
    const int excl = sh[tid] - sum;
    for (int c = 0; c < chunk; ++c) {
        int i = base + c;
        if (i < N) {
            int rs = excl + loc[c];
            row_start[i] = rs;
            cursor[i] = rs;
            dinv[i] = rsqrtf(1.0f + (float)cnt[i]);
        }
    }
    if (tid == 1023) row_start[N] = sh[1023];
}

__global__ void k_fill(const int* __restrict__ src, const int* __restrict__ dst,
                       int* __restrict__ cursor, int* __restrict__ csr_src, int E) {
    int e = blockIdx.x * blockDim.x + threadIdx.x;
    if (e < E) {
        int pos = atomicAdd(&cursor[dst[e]], 1);
        csr_src[pos] = src[e];
    }
}

// ---------------- fused prep: BN finalize (from stats) + Wt fold + wbias ----------------
__global__ void k_prep(const float* __restrict__ W,
                       const float* __restrict__ g, const float* __restrict__ be,
                       const float* __restrict__ cs, const float* __restrict__ cq,
                       ushort_t* __restrict__ Wt, float* __restrict__ wbias,
                       int K, int M, int Kp, int Mp, int yW, float invN)
{
    __shared__ float sm[256];
    if ((int)blockIdx.y < yW) {
        if (threadIdx.y == 0) {
            int kk = blockIdx.x * 64 + threadIdx.x;
            float sc = 0.f;
            if (kk < K) {
                float mu = cs[kk] * invN;
                float var = cq[kk] * invN - mu * mu;
                sc = g[kk] * rsqrtf(var + 1e-5f);
            }
            sm[threadIdx.x] = sc;
        }
        __syncthreads();
        int k = blockIdx.x * 64 + threadIdx.x;
        int j = blockIdx.y * 4 + threadIdx.y;
        if (k >= Kp || j >= Mp) return;
        float v = 0.f;
        if (k < K && j < M) v = sm[threadIdx.x] * W[(long)k * M + j];
        Wt[(long)j * Kp + k] = f2bf(v);
    } else {
        __shared__ float red[4][64];
        int t = threadIdx.y * 64 + threadIdx.x;
        for (int kk = t; kk < K; kk += 256) {
            float mu = cs[kk] * invN;
            float var = cq[kk] * invN - mu * mu;
            float sc = g[kk] * rsqrtf(var + 1e-5f);
            sm[kk] = be[kk] - mu * sc;
        }
        __syncthreads();
        int jl = t & 63, kg = t >> 6;
        int j = blockIdx.x * 64 + jl;
        float s = 0.f;
        if (j < M) {
            for (int k = kg; k < K; k += 4) s += sm[k] * W[(long)k * M + j];
        }
        red[kg][jl] = s;
        __syncthreads();
        if (kg == 0 && j < Mp) wbias[j] = red[0][jl] + red[1][jl] + red[2][jl] + red[3][jl];
    }
}

// ---------------- MFMA GEMM: 256 threads, 64x64 tile, LDS-staged B ----------------
template<int KP, bool F32A>
__global__ __launch_bounds__(256) void k_gemm_mfma(
    const void* __restrict__ Xin, const ushort_t* __restrict__ Wt,
    const float* __restrict__ wbias, const float* __restrict__ dinv,
    ushort_t* __restrict__ h2, int N, int Mp)
{
    typedef __attribute__((ext_vector_type(8))) short short8;
    typedef __attribute__((ext_vector_type(4))) float floatx4;
    constexpr int LSTR = KP + 16;
    __shared__ ushort_t Bs[64 * LSTR];

    const int tid = threadIdx.x;
    const int wave = tid >> 6, lane = tid & 63;
    const int m = lane & 15, quad = lane >> 4;
    const int i0 = blockIdx.x * 64 + wave * 16;
    const int j0 = blockIdx.y * 64;
    const int ncols = min(64, Mp - j0);
    const int ntiles = ncols >> 4;

    {
        const int cpr = KP / 8;
        const int chunks = ncols * cpr;
        for (int c = tid; c < chunks; c += 256) {
            int jj = c / cpr;
            int kk = (c - jj * cpr) * 8;
            *(short8*)(Bs + jj * LSTR + kk) =
                *(const short8*)(Wt + (long)(j0 + jj) * KP + kk);
        }
    }
    __syncthreads();

    if (i0 >= N) return;

    floatx4 acc[4];
    #pragma unroll
    for (int t = 0; t < 4; ++t) { acc[t].x = 0.f; acc[t].y = 0.f; acc[t].z = 0.f; acc[t].w = 0.f; }

    const int ra = min(i0 + m, N - 1);
    const ushort_t* arow_h = F32A ? nullptr : (const ushort_t*)Xin + (long)ra * KP + quad * 8;
    const float*    arow_f = F32A ? (const float*)Xin + (long)ra * KP + quad * 8 : nullptr;

    #pragma unroll
    for (int k0 = 0; k0 < KP; k0 += 32) {
        short8 av;
        if (F32A) {
            float4 f0 = *(const float4*)(arow_f + k0);
            float4 f1 = *(const float4*)(arow_f + k0 + 4);
            av[0] = (short)f2bf(f0.x); av[1] = (short)f2bf(f0.y);
            av[2] = (short)f2bf(f0.z); av[3] = (short)f2bf(f0.w);
            av[4] = (short)f2bf(f1.x); av[5] = (short)f2bf(f1.y);
            av[6] = (short)f2bf(f1.z); av[7] = (short)f2bf(f1.w);
        } else {
            av = *(const short8*)(arow_h + k0);
        }
        #pragma unroll
        for (int t = 0; t < 4; ++t) {
            if (t < ntiles) {
                short8 bv = *(const short8*)(Bs + (t * 16 + m) * LSTR + k0 + quad * 8);
                acc[t] = __builtin_amdgcn_mfma_f32_16x16x32_bf16(av, bv, acc[t], 0, 0, 0);
            }
        }
    }

    #pragma unroll
    for (int t = 0; t < 4; ++t) {
        if (t < ntiles) {
            int j = j0 + t * 16 + m;
            float wb = wbias[j];
            #pragma unroll
            for (int r = 0; r < 4; ++r) {
                int i = i0 + quad * 4 + r;
                if (i < N) h2[(long)i * Mp + j] = f2bf((acc[t][r] + wb) * dinv[i]);
            }
        }
    }
}

// ---------------- aggregation (CSR gather, uint4 = 8 bf16/thread, 8-deep unroll) ----------------
__device__ __forceinline__ void acc8(float* acc, uint4 w) {
    acc[0] += bf2f((ushort_t)(w.x & 0xffff)); acc[1] += bf2f((ushort_t)(w.x >> 16));
    acc[2] += bf2f((ushort_t)(w.y & 0xffff)); acc[3] += bf2f((ushort_t)(w.y >> 16));
    acc[4] += bf2f((ushort_t)(w.z & 0xffff)); acc[5] += bf2f((ushort_t)(w.z >> 16));
    acc[6] += bf2f((ushort_t)(w.w & 0xffff)); acc[7] += bf2f((ushort_t)(w.w >> 16));
}

__global__ __launch_bounds__(256) void k_agg(
    const int* __restrict__ row_start, const int* __restrict__ csr_src,
    const ushort_t* __restrict__ h2, int hs,
    const float* __restrict__ dinv, const float* __restrict__ b,
    ushort_t* __restrict__ tmpb, int ts,
    int N, int M, int Q, ull_t magic, uint_t sh)
{
    const uint_t g = blockIdx.x * 256 + threadIdx.x;
    const uint_t i = (uint_t)(((ull_t)g * magic) >> sh);
    const int jp = (int)(g - i * Q);
    if (i >= (uint_t)N) return;
    const int j0 = jp * 8;
    if (j0 >= M) {
        *(uint4*)(tmpb + (long)i * ts + j0) = make_uint4(0u, 0u, 0u, 0u);
        return;
    }
    const int s0 = row_start[i];
    const int s1 = row_start[i + 1];
    const ushort_t* hp = h2 + j0;
    float acc[8];
    {
        uint4 v = *(const uint4*)(hp + (long)i * hs);
        acc[0] = bf2f((ushort_t)(v.x & 0xffff)); acc[1] = bf2f((ushort_t)(v.x >> 16));
        acc[2] = bf2f((ushort_t)(v.y & 0xffff)); acc[3] = bf2f((ushort_t)(v.y >> 16));
        acc[4] = bf2f((ushort_t)(v.z & 0xffff)); acc[5] = bf2f((ushort_t)(v.z >> 16));
        acc[6] = bf2f((ushort_t)(v.w & 0xffff)); acc[7] = bf2f((ushort_t)(v.w >> 16));
    }
    int e = s0;
    for (; e + 7 < s1; e += 8) {
        int4 na = *(const int4*)(csr_src + e);
        int4 nb = *(const int4*)(csr_src + e + 4);
        uint4 w0 = *(const uint4*)(hp + (long)na.x * hs);
        uint4 w1 = *(const uint4*)(hp + (long)na.y * hs);
        uint4 w2 = *(const uint4*)(hp + (long)na.z * hs);
        uint4 w3 = *(const uint4*)(hp + (long)na.w * hs);
        uint4 w4 = *(const uint4*)(hp + (long)nb.x * hs);
        uint4 w5 = *(const uint4*)(hp + (long)nb.y * hs);
        uint4 w6 = *(const uint4*)(hp + (long)nb.z * hs);
        uint4 w7 = *(const uint4*)(hp + (long)nb.w * hs);
        acc8(acc, w0); acc8(acc, w1); acc8(acc, w2); acc8(acc, w3);
        acc8(acc, w4); acc8(acc, w5); acc8(acc, w6); acc8(acc, w7);
    }
    for (; e < s1; ++e) {
        uint4 w = *(const uint4*)(hp + (long)csr_src[e] * hs);
        acc8(acc, w);
    }
    const float di = dinv[i];
    ushort_t r[8];
    #pragma unroll
    for (int u = 0; u < 8; ++u) {
        float v = (j0 + u < M) ? fmaxf(acc[u] * di + b[j0 + u], 0.f) : 0.f;
        r[u] = f2bf(v);
    }
    uint4 pk;
    pk.x = (uint_t)r[0] | ((uint_t)r[1] << 16);
    pk.y = (uint_t)r[2] | ((uint_t)r[3] << 16);
    pk.z = (uint_t)r[4] | ((uint_t)r[5] << 16);
    pk.w = (uint_t)r[6] | ((uint_t)r[7] << 16);
    *(uint4*)(tmpb + (long)i * ts + j0) = pk;
}

// ---------------- BN stats: 16 rows/block for 4x occupancy ----------------
__global__ __launch_bounds__(256) void k_stats(
    const ushort_t* __restrict__ tmpb, int ts,
    float* __restrict__ cs, float* __restrict__ csq, int N)
{
    const int t = threadIdx.x;
    if (2 * t >= ts) return;
    const int i0 = blockIdx.x * 16;
    float s0 = 0.f, q0 = 0.f, s1 = 0.f, q1 = 0.f;
    #pragma unroll
    for (int r = 0; r < 16; ++r) {
        int i = i0 + r;
        if (i < N) {
            uint_t w = *(const uint_t*)(tmpb + (long)i * ts + 2 * t);
            float v0 = bf2f((ushort_t)(w & 0xffff));
            float v1 = bf2f((ushort_t)(w >> 16));
            s0 += v0; q0 += v0 * v0;
            s1 += v1; q1 += v1 * v1;
        }
    }
    atomicAdd(&cs[2 * t], s0);
    atomicAdd(&csq[2 * t], q0);
    atomicAdd(&cs[2 * t + 1], s1);
    atomicAdd(&csq[2 * t + 1], q1);
}

// ---------------- final layer: gather + bias + log_softmax ----------------
__global__ __launch_bounds__(256) void k_agg_final(
    const int* __restrict__ row_start, const int* __restrict__ csr_src,
    const ushort_t* __restrict__ h2, const float* __restrict__ dinv,
    const float* __restrict__ b, float* __restrict__ out, int N, int M)
{
    const int x = threadIdx.x;                 // 0..15
    const int i = blockIdx.x * 16 + threadIdx.y;
    if (i >= N) return;
    const int j0 = 2 * x, j1 = 2 * x + 1;
    uint_t v = *(const uint_t*)(h2 + (long)i * 32 + j0);
    float a0 = bf2f((ushort_t)(v & 0xffff));
    float a1 = bf2f((ushort_t)(v >> 16));
    const int s0 = row_start[i];
    const int s1 = row_start[i + 1];
    int e = s0;
    for (; e + 3 < s1; e += 4) {
        int4 n = *(const int4*)(csr_src + e);
        uint_t w0 = *(const uint_t*)(h2 + (long)n.x * 32 + j0);
        uint_t w1 = *(const uint_t*)(h2 + (long)n.y * 32 + j0);
        uint_t w2 = *(const uint_t*)(h2 + (long)n.z * 32 + j0);
        uint_t w3 = *(const uint_t*)(h2 + (long)n.w * 32 + j0);
        a0 += bf2f((ushort_t)(w0 & 0xffff)); a1 += bf2f((ushort_t)(w0 >> 16));
        a0 += bf2f((ushort_t)(w1 & 0xffff)); a1 += bf2f((ushort_t)(w1 >> 16));
        a0 += bf2f((ushort_t)(w2 & 0xffff)); a1 += bf2f((ushort_t)(w2 >> 16));
        a0 += bf2f((ushort_t)(w3 & 0xffff)); a1 += bf2f((ushort_t)(w3 >> 16));
    }
    for (; e < s1; ++e) {
        uint_t w = *(const uint_t*)(h2 + (long)csr_src[e] * 32 + j0);
        a0 += bf2f((ushort_t)(w & 0xffff)); a1 += bf2f((ushort_t)(w >> 16));
    }
    const float di = dinv[i];
    float r0 = (j0 < M) ? (a0 * di + b[j0]) : -INFINITY;
    float r1 = (j1 < M) ? (a1 * di + b[j1]) : -INFINITY;
    float m = fmaxf(r0, r1);
    #pragma unroll
    for (int msk = 1; msk < 16; msk <<= 1) m = fmaxf(m, __shfl_xor(m, msk, 16));
    float s = ((j0 < M) ? expf(r0 - m) : 0.f) + ((j1 < M) ? expf(r1 - m) : 0.f);
    #pragma unroll
    for (int msk = 1; msk < 16; msk <<= 1) s += __shfl_xor(s, msk, 16);
    const float l = logf(s) + m;
    if (j0 < M) out[(long)i * M + j0] = r0 - l;
    if (j1 < M) out[(long)i * M + j1] = r1 - l;
}

// ---------------- launch ----------------

static inline int pad16(int v) { return (v + 15) & ~15; }
static inline int pad32(int v) { return (v + 31) & ~31; }

extern "C" void kernel_launch(void* const* d_in, const int* in_sizes, int n_in,
                              void* d_out, int out_size, void* d_ws, size_t ws_size,
                              hipStream_t stream)
{
    const int dims[6] = {256, 220, 150, 100, 60, 17};
    const int N = in_sizes[0] / dims[0];      // 10000
    const int E = in_sizes[1] / 2;            // 320000

    const float* x  = (const float*)d_in[0];
    const int* ei   = (const int*)d_in[1];
    const int* srcv = ei;
    const int* dstv = ei + E;
    const float* Wl[5], *bl[5];
    for (int l = 0; l < 5; ++l) {
        Wl[l] = (const float*)d_in[2 + 2 * l];
        bl[l] = (const float*)d_in[3 + 2 * l];
    }
    const float* gl[4], *bel[4];
    for (int l = 0; l < 4; ++l) {
        gl[l]  = (const float*)d_in[12 + 2 * l];
        bel[l] = (const float*)d_in[13 + 2 * l];
    }
    float* out = (float*)d_out;

    // ---- workspace layout ----
    char* w = (char*)d_ws;
    const long NB  = ((long)N * 4 + 255) & ~255L;
    const long NB1 = ((long)(N + 1) * 4 + 255) & ~255L;
    const long EB  = ((long)E * 4 + 255) & ~255L;
    const long FBB = ((long)N * 224 * 2 + 255) & ~255L;
    const long WTB = ((long)224 * 256 * 2 + 255) & ~255L;

    long o = 0;
    float* dinv      = (float*)(w + o);  o += NB;
    float* stats     = (float*)(w + o);  o += 2048 * 4;
    float* wbias     = (float*)(w + o);  o += 1024;
    int*   cnt       = (int*)(w + o);    o += NB;
    int*   row_start = (int*)(w + o);    o += NB1;
    int*   cursor    = (int*)(w + o);    o += NB;
    int*   csr_src   = (int*)(w + o);    o += EB;
    ushort_t* Wt     = (ushort_t*)(w + o); o += WTB;
    ushort_t* h2     = (ushort_t*)(w + o); o += FBB;
    ushort_t* tmpb   = (ushort_t*)(w + o); o += FBB;

    const float invN = 1.0f / (float)N;

    k_init<<<224, 256, 0, stream>>>(Wl[0], cnt, stats, wbias, Wt, N);
    k_hist<<<(E / 4 + 255) / 256, 256, 0, stream>>>(dstv, cnt, E);
    k_scan<<<1, 1024, 0, stream>>>(cnt, row_start, cursor, dinv, N);
    k_fill<<<(E + 255) / 256, 256, 0, stream>>>(srcv, dstv, cursor, csr_src, E);

    for (int l = 0; l < 5; ++l) {
        const int K  = dims[l];
        const int M  = dims[l + 1];
        const int Kp = pad32(K);
        const int Mp = pad16(M);
        const int ts = (l < 4) ? pad32(M) : 32;

        if (l > 0) {
            const int yW = (Mp + 3) / 4;
            k_prep<<<dim3((Kp + 63) / 64, yW + 1), dim3(64, 4), 0, stream>>>(
                Wl[l], gl[l - 1], bel[l - 1],
                stats + (l - 1) * 512, stats + (l - 1) * 512 + 256,
                Wt, wbias, K, M, Kp, Mp, yW, invN);
        }

        dim3 gg((N + 63) / 64, (Mp + 63) / 64);
        if (l == 0) {
            k_gemm_mfma<256, true><<<gg, 256, 0, stream>>>(x, Wt, wbias, dinv, h2, N, Mp);
        } else {
            switch (Kp) {
                case 224: k_gemm_mfma<224, false><<<gg, 256, 0, stream>>>(tmpb, Wt, wbias, dinv, h2, N, Mp); break;
                case 160: k_gemm_mfma<160, false><<<gg, 256, 0, stream>>>(tmpb, Wt, wbias, dinv, h2, N, Mp); break;
                case 128: k_gemm_mfma<128, false><<<gg, 256, 0, stream>>>(tmpb, Wt, wbias, dinv, h2, N, Mp); break;
                case  64: k_gemm_mfma< 64, false><<<gg, 256, 0, stream>>>(tmpb, Wt, wbias, dinv, h2, N, Mp); break;
            }
        }

        if (l < 4) {
            const int Q = ts / 8;
            uint_t shmt = 0;
            while ((1u << shmt) < (uint_t)Q) ++shmt;
            shmt += 32;
            const ull_t magic = ((1ULL << shmt) + Q - 1) / (ull_t)Q;   // 64-bit (pow2 Q!)
            const long total = (long)N * Q;
            k_agg<<<(int)((total + 255) / 256), 256, 0, stream>>>(
                row_start, csr_src, h2, Mp, dinv, bl[l], tmpb, ts, N, M, Q, magic, shmt);
            k_stats<<<(N + 15) / 16, 256, 0, stream>>>(tmpb, ts,
                stats + l * 512, stats + l * 512 + 256, N);
        } else {
            k_agg_final<<<(N + 15) / 16, dim3(16, 16), 0, stream>>>(
                row_start, csr_src, h2, dinv, bl[l], out, N, M);
        }
    }
}

// Round 14
// 414.158 us; speedup vs baseline: 1.0680x; 1.0680x over previous
//
#include <hip/hip_runtime.h>
#include <math.h>

typedef unsigned short ushort_t;
typedef unsigned int uint_t;
typedef unsigned long long ull_t;

#define FXP 1048576.0   // 2^20 fixed-point scale for deterministic BN stats

__device__ __forceinline__ float bf2f(ushort_t u) {
    union { uint_t i; float f; } x; x.i = ((uint_t)u) << 16; return x.f;
}
__device__ __forceinline__ ushort_t f2bf(float f) {
    union { float f; uint_t i; } x; x.f = f;
    uint_t r = x.i + 0x7FFFu + ((x.i >> 16) & 1u);
    return (ushort_t)(r >> 16);
}

// ---------------- init: zero cnt/stats(ull)/wbias + prep layer-0 Wt ----------------
__global__ __launch_bounds__(256) void k_init(
    const float* __restrict__ W0, int* __restrict__ cnt, ull_t* __restrict__ stats,
    float* __restrict__ wbias, ushort_t* __restrict__ Wt, int N)
{
    const int gt = blockIdx.x * 256 + threadIdx.x;
    const int gth = gridDim.x * 256;
    for (int i = gt; i < N; i += gth) cnt[i] = 0;
    for (int i = gt; i < 2048; i += gth) stats[i] = 0ull;
    if (gt < 256) wbias[gt] = 0.f;          // layer-0 wbias = 0
    // prep0: Wt[j][k] = bf16(W0[k][j]); K=256, M=220, Mp=224
    for (int idx = gt; idx < 224 * 256; idx += gth) {
        int j = idx >> 8;
        int k = idx & 255;
        float v = (j < 220) ? W0[(long)k * 220 + j] : 0.f;
        Wt[idx] = f2bf(v);
    }
}

__global__ void k_hist(const int* __restrict__ dst, int* __restrict__ cnt, int E) {
    int e = blockIdx.x * blockDim.x + threadIdx.x;
    if (e < E) atomicAdd(&cnt[dst[e]], 1);   // int atomics: commutative -> deterministic
}

__global__ __launch_bounds__(1024) void k_scan(
    const int* __restrict__ cnt, int* __restrict__ row_start,
    int* __restrict__ cursor, float* __restrict__ dinv, int N)
{
    __shared__ int sh[1024];
    const int tid = threadIdx.x;
    const int chunk = (N + 1023) >> 10;
    int loc[16];
    const int base = tid * chunk;
    int sum = 0;
    for (int c = 0; c < chunk; ++c) {
        int i = base + c;
        int v = (i < N) ? cnt[i] : 0;
        loc[c] = sum;
        sum += v;
    }
    sh[tid] = sum;
    __syncthreads();
    for (int off = 1; off < 1024; off <<= 1) {
        int v = (tid >= off) ? sh[tid - off] : 0;
        __syncthreads();
        sh[tid] += v;
        __syncthreads();
    }
    const int excl = sh[tid] - sum;
    for (int c = 0; c < chunk; ++c) {
        int i = base + c;
        if (i < N) {
            int rs = excl + loc[c];
            row_start[i] = rs;
            cursor[i] = rs;
            dinv[i] = rsqrtf(1.0f + (float)cnt[i]);
        }
    }
    if (tid == 1023) row_start[N] = sh[1023];
}

__global__ void k_fill(const int* __restrict__ src, const int* __restrict__ dst,
                       int* __restrict__ cursor, int* __restrict__ csr_src, int E) {
    int e = blockIdx.x * blockDim.x + threadIdx.x;
    if (e < E) {
        int pos = atomicAdd(&cursor[dst[e]], 1);   // position nondeterministic -> erased by k_sort
        csr_src[pos] = src[e];
    }
}

// ---------------- sort each CSR row (canonical order -> deterministic sums) ----------------
// one 64-lane block per row; odd-even transposition in LDS; skip deg>256 (prob ~0)
__global__ __launch_bounds__(64) void k_sort(
    const int* __restrict__ row_start, int* __restrict__ csr_src, int N)
{
    __shared__ int buf[256];
    const int r = blockIdx.x;
    if (r >= N) return;
    const int s0 = row_start[r], s1 = row_start[r + 1];
    const int n = s1 - s0;
    if (n <= 1 || n > 256) return;              // uniform across block: no barrier hazard
    for (int i = threadIdx.x; i < n; i += 64) buf[i] = csr_src[s0 + i];
    __syncthreads();
    for (int p = 0; p < n; ++p) {
        const int st = p & 1;
        for (int i = st + 2 * (int)threadIdx.x; i + 1 < n; i += 128) {
            int a = buf[i], b = buf[i + 1];
            if (a > b) { buf[i] = b; buf[i + 1] = a; }
        }
        __syncthreads();
    }
    for (int i = threadIdx.x; i < n; i += 64) csr_src[s0 + i] = buf[i];
}

// ---------------- fused prep: BN finalize (fixed-point stats) + Wt fold + wbias ----------------
__global__ void k_prep(const float* __restrict__ W,
                       const float* __restrict__ g, const float* __restrict__ be,
                       const ull_t* __restrict__ cs, const ull_t* __restrict__ cq,
                       ushort_t* __restrict__ Wt, float* __restrict__ wbias,
                       int K, int M, int Kp, int Mp, int yW, float invN)
{
    __shared__ float sm[256];
    if ((int)blockIdx.y < yW) {
        if (threadIdx.y == 0) {
            int kk = blockIdx.x * 64 + threadIdx.x;
            float sc = 0.f;
            if (kk < K) {
                double c  = (double)cs[kk] * (1.0 / FXP);
                double c2 = (double)cq[kk] * (1.0 / FXP);
                float mu = (float)(c * (double)invN);
                float var = (float)(c2 * (double)invN) - mu * mu;
                sc = g[kk] * rsqrtf(var + 1e-5f);
            }
            sm[threadIdx.x] = sc;
        }
        __syncthreads();
        int k = blockIdx.x * 64 + threadIdx.x;
        int j = blockIdx.y * 4 + threadIdx.y;
        if (k >= Kp || j >= Mp) return;
        float v = 0.f;
        if (k < K && j < M) v = sm[threadIdx.x] * W[(long)k * M + j];
        Wt[(long)j * Kp + k] = f2bf(v);
    } else {
        __shared__ float red[4][64];
        int t = threadIdx.y * 64 + threadIdx.x;
        for (int kk = t; kk < K; kk += 256) {
            double c  = (double)cs[kk] * (1.0 / FXP);
            double c2 = (double)cq[kk] * (1.0 / FXP);
            float mu = (float)(c * (double)invN);
            float var = (float)(c2 * (double)invN) - mu * mu;
            float sc = g[kk] * rsqrtf(var + 1e-5f);
            sm[kk] = be[kk] - mu * sc;
        }
        __syncthreads();
        int jl = t & 63, kg = t >> 6;
        int j = blockIdx.x * 64 + jl;
        float s = 0.f;
        if (j < M) {
            for (int k = kg; k < K; k += 4) s += sm[k] * W[(long)k * M + j];
        }
        red[kg][jl] = s;
        __syncthreads();
        if (kg == 0 && j < Mp) wbias[j] = red[0][jl] + red[1][jl] + red[2][jl] + red[3][jl];
    }
}

// ---------------- MFMA GEMM: 256 threads, 64x64 tile, LDS-staged B ----------------
template<int KP, bool F32A>
__global__ __launch_bounds__(256) void k_gemm_mfma(
    const void* __restrict__ Xin, const ushort_t* __restrict__ Wt,
    const float* __restrict__ wbias, const float* __restrict__ dinv,
    ushort_t* __restrict__ h2, int N, int Mp)
{
    typedef __attribute__((ext_vector_type(8))) short short8;
    typedef __attribute__((ext_vector_type(4))) float floatx4;
    constexpr int LSTR = KP + 16;
    __shared__ ushort_t Bs[64 * LSTR];

    const int tid = threadIdx.x;
    const int wave = tid >> 6, lane = tid & 63;
    const int m = lane & 15, quad = lane >> 4;
    const int i0 = blockIdx.x * 64 + wave * 16;
    const int j0 = blockIdx.y * 64;
    const int ncols = min(64, Mp - j0);
    const int ntiles = ncols >> 4;

    {
        const int cpr = KP / 8;
        const int chunks = ncols * cpr;
        for (int c = tid; c < chunks; c += 256) {
            int jj = c / cpr;
            int kk = (c - jj * cpr) * 8;
            *(short8*)(Bs + jj * LSTR + kk) =
                *(const short8*)(Wt + (long)(j0 + jj) * KP + kk);
        }
    }
    __syncthreads();

    if (i0 >= N) return;

    floatx4 acc[4];
    #pragma unroll
    for (int t = 0; t < 4; ++t) { acc[t].x = 0.f; acc[t].y = 0.f; acc[t].z = 0.f; acc[t].w = 0.f; }

    const int ra = min(i0 + m, N - 1);
    const ushort_t* arow_h = F32A ? nullptr : (const ushort_t*)Xin + (long)ra * KP + quad * 8;
    const float*    arow_f = F32A ? (const float*)Xin + (long)ra * KP + quad * 8 : nullptr;

    #pragma unroll
    for (int k0 = 0; k0 < KP; k0 += 32) {
        short8 av;
        if (F32A) {
            float4 f0 = *(const float4*)(arow_f + k0);
            float4 f1 = *(const float4*)(arow_f + k0 + 4);
            av[0] = (short)f2bf(f0.x); av[1] = (short)f2bf(f0.y);
            av[2] = (short)f2bf(f0.z); av[3] = (short)f2bf(f0.w);
            av[4] = (short)f2bf(f1.x); av[5] = (short)f2bf(f1.y);
            av[6] = (short)f2bf(f1.z); av[7] = (short)f2bf(f1.w);
        } else {
            av = *(const short8*)(arow_h + k0);
        }
        #pragma unroll
        for (int t = 0; t < 4; ++t) {
            if (t < ntiles) {
                short8 bv = *(const short8*)(Bs + (t * 16 + m) * LSTR + k0 + quad * 8);
                acc[t] = __builtin_amdgcn_mfma_f32_16x16x32_bf16(av, bv, acc[t], 0, 0, 0);
            }
        }
    }

    #pragma unroll
    for (int t = 0; t < 4; ++t) {
        if (t < ntiles) {
            int j = j0 + t * 16 + m;
            float wb = wbias[j];
            #pragma unroll
            for (int r = 0; r < 4; ++r) {
                int i = i0 + quad * 4 + r;
                if (i < N) h2[(long)i * Mp + j] = f2bf((acc[t][r] + wb) * dinv[i]);
            }
        }
    }
}

// ---------------- aggregation (CSR gather, uint4 = 8 bf16/thread) ----------------
__device__ __forceinline__ void acc8(float* acc, uint4 w) {
    acc[0] += bf2f((ushort_t)(w.x & 0xffff)); acc[1] += bf2f((ushort_t)(w.x >> 16));
    acc[2] += bf2f((ushort_t)(w.y & 0xffff)); acc[3] += bf2f((ushort_t)(w.y >> 16));
    acc[4] += bf2f((ushort_t)(w.z & 0xffff)); acc[5] += bf2f((ushort_t)(w.z >> 16));
    acc[6] += bf2f((ushort_t)(w.w & 0xffff)); acc[7] += bf2f((ushort_t)(w.w >> 16));
}

__global__ __launch_bounds__(256) void k_agg(
    const int* __restrict__ row_start, const int* __restrict__ csr_src,
    const ushort_t* __restrict__ h2, int hs,
    const float* __restrict__ dinv, const float* __restrict__ b,
    ushort_t* __restrict__ tmpb, int ts,
    int N, int M, int Q, ull_t magic, uint_t sh)
{
    const uint_t g = blockIdx.x * 256 + threadIdx.x;
    const uint_t i = (uint_t)(((ull_t)g * magic) >> sh);
    const int jp = (int)(g - i * Q);
    if (i >= (uint_t)N) return;
    const int j0 = jp * 8;
    if (j0 >= M) {
        *(uint4*)(tmpb + (long)i * ts + j0) = make_uint4(0u, 0u, 0u, 0u);
        return;
    }
    const int s0 = row_start[i];
    const int s1 = row_start[i + 1];
    const ushort_t* hp = h2 + j0;
    float acc[8];
    {
        uint4 v = *(const uint4*)(hp + (long)i * hs);
        acc[0] = bf2f((ushort_t)(v.x & 0xffff)); acc[1] = bf2f((ushort_t)(v.x >> 16));
        acc[2] = bf2f((ushort_t)(v.y & 0xffff)); acc[3] = bf2f((ushort_t)(v.y >> 16));
        acc[4] = bf2f((ushort_t)(v.z & 0xffff)); acc[5] = bf2f((ushort_t)(v.z >> 16));
        acc[6] = bf2f((ushort_t)(v.w & 0xffff)); acc[7] = bf2f((ushort_t)(v.w >> 16));
    }
    int e = s0;
    for (; e + 3 < s1; e += 4) {
        int n0 = csr_src[e], n1 = csr_src[e + 1], n2 = csr_src[e + 2], n3 = csr_src[e + 3];
        uint4 w0 = *(const uint4*)(hp + (long)n0 * hs);
        uint4 w1 = *(const uint4*)(hp + (long)n1 * hs);
        uint4 w2 = *(const uint4*)(hp + (long)n2 * hs);
        uint4 w3 = *(const uint4*)(hp + (long)n3 * hs);
        acc8(acc, w0); acc8(acc, w1); acc8(acc, w2); acc8(acc, w3);
    }
    for (; e < s1; ++e) {
        uint4 w = *(const uint4*)(hp + (long)csr_src[e] * hs);
        acc8(acc, w);
    }
    const float di = dinv[i];
    ushort_t r[8];
    #pragma unroll
    for (int u = 0; u < 8; ++u) {
        float v = (j0 + u < M) ? fmaxf(acc[u] * di + b[j0 + u], 0.f) : 0.f;
        r[u] = f2bf(v);
    }
    uint4 pk;
    pk.x = (uint_t)r[0] | ((uint_t)r[1] << 16);
    pk.y = (uint_t)r[2] | ((uint_t)r[3] << 16);
    pk.z = (uint_t)r[4] | ((uint_t)r[5] << 16);
    pk.w = (uint_t)r[6] | ((uint_t)r[7] << 16);
    *(uint4*)(tmpb + (long)i * ts + j0) = pk;
}

// ---------------- BN stats: fixed-point ull atomics (order-independent => deterministic) ----------------
__global__ __launch_bounds__(256) void k_stats(
    const ushort_t* __restrict__ tmpb, int ts,
    ull_t* __restrict__ cs, ull_t* __restrict__ cq, int N)
{
    const int t = threadIdx.x;
    if (2 * t >= ts) return;
    const int i0 = blockIdx.x * 64;
    float s0 = 0.f, q0 = 0.f, s1 = 0.f, q1 = 0.f;
    for (int r = 0; r < 64; ++r) {
        int i = i0 + r;
        if (i < N) {
            uint_t w = *(const uint_t*)(tmpb + (long)i * ts + 2 * t);
            float v0 = bf2f((ushort_t)(w & 0xffff));
            float v1 = bf2f((ushort_t)(w >> 16));
            s0 += v0; q0 += v0 * v0;
            s1 += v1; q1 += v1 * v1;
        }
    }
    // post-ReLU partials are >= 0: fixed-point encode is safe in ull
    atomicAdd(&cs[2 * t],     (ull_t)llround((double)s0 * FXP));
    atomicAdd(&cq[2 * t],     (ull_t)llround((double)q0 * FXP));
    atomicAdd(&cs[2 * t + 1], (ull_t)llround((double)s1 * FXP));
    atomicAdd(&cq[2 * t + 1], (ull_t)llround((double)q1 * FXP));
}

// ---------------- final layer: gather + bias + log_softmax ----------------
__global__ __launch_bounds__(256) void k_agg_final(
    const int* __restrict__ row_start, const int* __restrict__ csr_src,
    const ushort_t* __restrict__ h2, const float* __restrict__ dinv,
    const float* __restrict__ b, float* __restrict__ out, int N, int M)
{
    const int x = threadIdx.x;                 // 0..15
    const int i = blockIdx.x * 16 + threadIdx.y;
    if (i >= N) return;
    const int j0 = 2 * x, j1 = 2 * x + 1;
    uint_t v = *(const uint_t*)(h2 + (long)i * 32 + j0);
    float a0 = bf2f((ushort_t)(v & 0xffff));
    float a1 = bf2f((ushort_t)(v >> 16));
    const int s0 = row_start[i];
    const int s1 = row_start[i + 1];
    int e = s0;
    for (; e + 1 < s1; e += 2) {
        int n0 = csr_src[e], n1 = csr_src[e + 1];
        uint_t w0 = *(const uint_t*)(h2 + (long)n0 * 32 + j0);
        uint_t w1 = *(const uint_t*)(h2 + (long)n1 * 32 + j0);
        a0 += bf2f((ushort_t)(w0 & 0xffff)); a1 += bf2f((ushort_t)(w0 >> 16));
        a0 += bf2f((ushort_t)(w1 & 0xffff)); a1 += bf2f((ushort_t)(w1 >> 16));
    }
    for (; e < s1; ++e) {
        uint_t w = *(const uint_t*)(h2 + (long)csr_src[e] * 32 + j0);
        a0 += bf2f((ushort_t)(w & 0xffff)); a1 += bf2f((ushort_t)(w >> 16));
    }
    const float di = dinv[i];
    float r0 = (j0 < M) ? (a0 * di + b[j0]) : -INFINITY;
    float r1 = (j1 < M) ? (a1 * di + b[j1]) : -INFINITY;
    float m = fmaxf(r0, r1);
    #pragma unroll
    for (int msk = 1; msk < 16; msk <<= 1) m = fmaxf(m, __shfl_xor(m, msk, 16));
    float s = ((j0 < M) ? expf(r0 - m) : 0.f) + ((j1 < M) ? expf(r1 - m) : 0.f);
    #pragma unroll
    for (int msk = 1; msk < 16; msk <<= 1) s += __shfl_xor(s, msk, 16);
    const float l = logf(s) + m;
    if (j0 < M) out[(long)i * M + j0] = r0 - l;
    if (j1 < M) out[(long)i * M + j1] = r1 - l;
}

// ---------------- launch ----------------

static inline int pad16(int v) { return (v + 15) & ~15; }
static inline int pad32(int v) { return (v + 31) & ~31; }

extern "C" void kernel_launch(void* const* d_in, const int* in_sizes, int n_in,
                              void* d_out, int out_size, void* d_ws, size_t ws_size,
                              hipStream_t stream)
{
    const int dims[6] = {256, 220, 150, 100, 60, 17};
    const int N = in_sizes[0] / dims[0];      // 10000
    const int E = in_sizes[1] / 2;            // 320000

    const float* x  = (const float*)d_in[0];
    const int* ei   = (const int*)d_in[1];
    const int* srcv = ei;
    const int* dstv = ei + E;
    const float* Wl[5], *bl[5];
    for (int l = 0; l < 5; ++l) {
        Wl[l] = (const float*)d_in[2 + 2 * l];
        bl[l] = (const float*)d_in[3 + 2 * l];
    }
    const float* gl[4], *bel[4];
    for (int l = 0; l < 4; ++l) {
        gl[l]  = (const float*)d_in[12 + 2 * l];
        bel[l] = (const float*)d_in[13 + 2 * l];
    }
    float* out = (float*)d_out;

    // ---- workspace layout ----
    char* w = (char*)d_ws;
    const long NB  = ((long)N * 4 + 255) & ~255L;
    const long NB1 = ((long)(N + 1) * 4 + 255) & ~255L;
    const long EB  = ((long)E * 4 + 255) & ~255L;
    const long FBB = ((long)N * 224 * 2 + 255) & ~255L;
    const long WTB = ((long)224 * 256 * 2 + 255) & ~255L;

    long o = 0;
    float* dinv      = (float*)(w + o);  o += NB;
    ull_t* stats     = (ull_t*)(w + o);  o += 2048 * 8;   // 4 layers x (cs[256]+cq[256]) ull
    float* wbias     = (float*)(w + o);  o += 1024;
    int*   cnt       = (int*)(w + o);    o += NB;
    int*   row_start = (int*)(w + o);    o += NB1;
    int*   cursor    = (int*)(w + o);    o += NB;
    int*   csr_src   = (int*)(w + o);    o += EB;
    ushort_t* Wt     = (ushort_t*)(w + o); o += WTB;
    ushort_t* h2     = (ushort_t*)(w + o); o += FBB;
    ushort_t* tmpb   = (ushort_t*)(w + o); o += FBB;

    const float invN = 1.0f / (float)N;

    k_init<<<224, 256, 0, stream>>>(Wl[0], cnt, stats, wbias, Wt, N);
    k_hist<<<(E + 255) / 256, 256, 0, stream>>>(dstv, cnt, E);
    k_scan<<<1, 1024, 0, stream>>>(cnt, row_start, cursor, dinv, N);
    k_fill<<<(E + 255) / 256, 256, 0, stream>>>(srcv, dstv, cursor, csr_src, E);
    k_sort<<<N, 64, 0, stream>>>(row_start, csr_src, N);

    for (int l = 0; l < 5; ++l) {
        const int K  = dims[l];
        const int M  = dims[l + 1];
        const int Kp = pad32(K);
        const int Mp = pad16(M);
        const int ts = (l < 4) ? pad32(M) : 32;

        if (l > 0) {
            const int yW = (Mp + 3) / 4;
            k_prep<<<dim3((Kp + 63) / 64, yW + 1), dim3(64, 4), 0, stream>>>(
                Wl[l], gl[l - 1], bel[l - 1],
                stats + (l - 1) * 512, stats + (l - 1) * 512 + 256,
                Wt, wbias, K, M, Kp, Mp, yW, invN);
        }

        dim3 gg((N + 63) / 64, (Mp + 63) / 64);
        if (l == 0) {
            k_gemm_mfma<256, true><<<gg, 256, 0, stream>>>(x, Wt, wbias, dinv, h2, N, Mp);
        } else {
            switch (Kp) {
                case 224: k_gemm_mfma<224, false><<<gg, 256, 0, stream>>>(tmpb, Wt, wbias, dinv, h2, N, Mp); break;
                case 160: k_gemm_mfma<160, false><<<gg, 256, 0, stream>>>(tmpb, Wt, wbias, dinv, h2, N, Mp); break;
                case 128: k_gemm_mfma<128, false><<<gg, 256, 0, stream>>>(tmpb, Wt, wbias, dinv, h2, N, Mp); break;
                case  64: k_gemm_mfma< 64, false><<<gg, 256, 0, stream>>>(tmpb, Wt, wbias, dinv, h2, N, Mp); break;
            }
        }

        if (l < 4) {
            const int Q = ts / 8;
            uint_t shmt = 0;
            while ((1u << shmt) < (uint_t)Q) ++shmt;
            shmt += 32;
            const ull_t magic = ((1ULL << shmt) + Q - 1) / (ull_t)Q;   // 64-bit (pow2 Q!)
            const long total = (long)N * Q;
            k_agg<<<(int)((total + 255) / 256), 256, 0, stream>>>(
                row_start, csr_src, h2, Mp, dinv, bl[l], tmpb, ts, N, M, Q, magic, shmt);
            k_stats<<<(N + 63) / 64, 256, 0, stream>>>(tmpb, ts,
                stats + l * 512, stats + l * 512 + 256, N);
        } else {
            k_agg_final<<<(N + 15) / 16, dim3(16, 16), 0, stream>>>(
                row_start, csr_src, h2, dinv, bl[l], out, N, M);
        }
    }
}

// Round 15
// 402.349 us; speedup vs baseline: 1.0993x; 1.0293x over previous
//
#include <hip/hip_runtime.h>
#include <math.h>
#include <limits.h>

typedef unsigned short ushort_t;
typedef unsigned int uint_t;
typedef unsigned long long ull_t;

#define FXP 1048576.0   // 2^20 fixed-point scale for deterministic BN stats

__device__ __forceinline__ float bf2f(ushort_t u) {
    union { uint_t i; float f; } x; x.i = ((uint_t)u) << 16; return x.f;
}
__device__ __forceinline__ ushort_t f2bf(float f) {
    union { float f; uint_t i; } x; x.f = f;
    uint_t r = x.i + 0x7FFFu + ((x.i >> 16) & 1u);
    return (ushort_t)(r >> 16);
}

// ---------------- init: zero cnt/stats(ull)/wbias + prep layer-0 Wt ----------------
__global__ __launch_bounds__(256) void k_init(
    const float* __restrict__ W0, int* __restrict__ cnt, ull_t* __restrict__ stats,
    float* __restrict__ wbias, ushort_t* __restrict__ Wt, int N)
{
    const int gt = blockIdx.x * 256 + threadIdx.x;
    const int gth = gridDim.x * 256;
    for (int i = gt; i < N; i += gth) cnt[i] = 0;
    for (int i = gt; i < 2048; i += gth) stats[i] = 0ull;
    if (gt < 256) wbias[gt] = 0.f;          // layer-0 wbias = 0
    // prep0: Wt[j][k] = bf16(W0[k][j]); K=256, M=220, Mp=224
    for (int idx = gt; idx < 224 * 256; idx += gth) {
        int j = idx >> 8;
        int k = idx & 255;
        float v = (j < 220) ? W0[(long)k * 220 + j] : 0.f;
        Wt[idx] = f2bf(v);
    }
}

__global__ void k_hist(const int* __restrict__ dst, int* __restrict__ cnt, int E) {
    int e = blockIdx.x * blockDim.x + threadIdx.x;
    if (e < E) atomicAdd(&cnt[dst[e]], 1);   // int atomics: commutative -> deterministic
}

__global__ __launch_bounds__(1024) void k_scan(
    const int* __restrict__ cnt, int* __restrict__ row_start,
    int* __restrict__ cursor, float* __restrict__ dinv, int N)
{
    __shared__ int sh[1024];
    const int tid = threadIdx.x;
    const int chunk = (N + 1023) >> 10;
    int loc[16];
    const int base = tid * chunk;
    int sum = 0;
    for (int c = 0; c < chunk; ++c) {
        int i = base + c;
        int v = (i < N) ? cnt[i] : 0;
        loc[c] = sum;
        sum += v;
    }
    sh[tid] = sum;
    __syncthreads();
    for (int off = 1; off < 1024; off <<= 1) {
        int v = (tid >= off) ? sh[tid - off] : 0;
        __syncthreads();
        sh[tid] += v;
        __syncthreads();
    }
    const int excl = sh[tid] - sum;
    for (int c = 0; c < chunk; ++c) {
        int i = base + c;
        if (i < N) {
            int rs = excl + loc[c];
            row_start[i] = rs;
            cursor[i] = rs;
            dinv[i] = rsqrtf(1.0f + (float)cnt[i]);
        }
    }
    if (tid == 1023) row_start[N] = sh[1023];
}

__global__ void k_fill(const int* __restrict__ src, const int* __restrict__ dst,
                       int* __restrict__ cursor, int* __restrict__ csr_src, int E) {
    int e = blockIdx.x * blockDim.x + threadIdx.x;
    if (e < E) {
        int pos = atomicAdd(&cursor[dst[e]], 1);   // position nondeterministic -> erased by k_sort
        csr_src[pos] = src[e];
    }
}

// ---------------- sort each CSR row (canonical order -> deterministic sums) ----------------
// one wave per row. deg<=64: in-register bitonic via shuffles (no barriers, no LDS).
// deg>64 (P ~1e-7 at mean 32): LDS odd-even fallback, wave-synchronous (single wave).
__global__ __launch_bounds__(64) void k_sort(
    const int* __restrict__ row_start, int* __restrict__ csr_src, int N)
{
    __shared__ int buf[512];
    const int r = blockIdx.x;
    if (r >= N) return;
    const int s0 = row_start[r], s1 = row_start[r + 1];
    const int n = s1 - s0;
    if (n <= 1) return;
    const int l = threadIdx.x;
    if (n <= 64) {
        int v = (l < n) ? csr_src[s0 + l] : INT_MAX;
        #pragma unroll
        for (int k = 2; k <= 64; k <<= 1) {
            #pragma unroll
            for (int j = k >> 1; j > 0; j >>= 1) {
                int o = __shfl_xor(v, j, 64);
                bool up = ((l & k) == 0);
                bool lower = ((l & j) == 0);
                bool takeMin = (lower == up);
                v = takeMin ? min(v, o) : max(v, o);
            }
        }
        if (l < n) csr_src[s0 + l] = v;
    } else if (n <= 512) {
        // single-wave odd-even in LDS (wave-synchronous; no __syncthreads needed)
        for (int i = l; i < n; i += 64) buf[i] = csr_src[s0 + i];
        for (int p = 0; p < n; ++p) {
            const int st = p & 1;
            for (int i = st + 2 * l; i + 1 < n; i += 128) {
                int a = buf[i], b = buf[i + 1];
                if (a > b) { buf[i] = b; buf[i + 1] = a; }
            }
        }
        for (int i = l; i < n; i += 64) csr_src[s0 + i] = buf[i];
    }
}

// ---------------- fused prep: BN finalize (fixed-point stats) + Wt fold + wbias ----------------
__global__ void k_prep(const float* __restrict__ W,
                       const float* __restrict__ g, const float* __restrict__ be,
                       const ull_t* __restrict__ cs, const ull_t* __restrict__ cq,
                       ushort_t* __restrict__ Wt, float* __restrict__ wbias,
                       int K, int M, int Kp, int Mp, int yW, float invN)
{
    __shared__ float sm[256];
    if ((int)blockIdx.y < yW) {
        if (threadIdx.y == 0) {
            int kk = blockIdx.x * 64 + threadIdx.x;
            float sc = 0.f;
            if (kk < K) {
                double c  = (double)cs[kk] * (1.0 / FXP);
                double c2 = (double)cq[kk] * (1.0 / FXP);
                float mu = (float)(c * (double)invN);
                float var = (float)(c2 * (double)invN) - mu * mu;
                sc = g[kk] * rsqrtf(var + 1e-5f);
            }
            sm[threadIdx.x] = sc;
        }
        __syncthreads();
        int k = blockIdx.x * 64 + threadIdx.x;
        int j = blockIdx.y * 4 + threadIdx.y;
        if (k >= Kp || j >= Mp) return;
        float v = 0.f;
        if (k < K && j < M) v = sm[threadIdx.x] * W[(long)k * M + j];
        Wt[(long)j * Kp + k] = f2bf(v);
    } else {
        __shared__ float red[4][64];
        int t = threadIdx.y * 64 + threadIdx.x;
        for (int kk = t; kk < K; kk += 256) {
            double c  = (double)cs[kk] * (1.0 / FXP);
            double c2 = (double)cq[kk] * (1.0 / FXP);
            float mu = (float)(c * (double)invN);
            float var = (float)(c2 * (double)invN) - mu * mu;
            float sc = g[kk] * rsqrtf(var + 1e-5f);
            sm[kk] = be[kk] - mu * sc;
        }
        __syncthreads();
        int jl = t & 63, kg = t >> 6;
        int j = blockIdx.x * 64 + jl;
        float s = 0.f;
        if (j < M) {
            for (int k = kg; k < K; k += 4) s += sm[k] * W[(long)k * M + j];
        }
        red[kg][jl] = s;
        __syncthreads();
        if (kg == 0 && j < Mp) wbias[j] = red[0][jl] + red[1][jl] + red[2][jl] + red[3][jl];
    }
}

// ---------------- MFMA GEMM: 256 threads, 64x64 tile, LDS-staged B ----------------
template<int KP, bool F32A>
__global__ __launch_bounds__(256) void k_gemm_mfma(
    const void* __restrict__ Xin, const ushort_t* __restrict__ Wt,
    const float* __restrict__ wbias, const float* __restrict__ dinv,
    ushort_t* __restrict__ h2, int N, int Mp)
{
    typedef __attribute__((ext_vector_type(8))) short short8;
    typedef __attribute__((ext_vector_type(4))) float floatx4;
    constexpr int LSTR = KP + 16;
    __shared__ ushort_t Bs[64 * LSTR];

    const int tid = threadIdx.x;
    const int wave = tid >> 6, lane = tid & 63;
    const int m = lane & 15, quad = lane >> 4;
    const int i0 = blockIdx.x * 64 + wave * 16;
    const int j0 = blockIdx.y * 64;
    const int ncols = min(64, Mp - j0);
    const int ntiles = ncols >> 4;

    {
        const int cpr = KP / 8;
        const int chunks = ncols * cpr;
        for (int c = tid; c < chunks; c += 256) {
            int jj = c / cpr;
            int kk = (c - jj * cpr) * 8;
            *(short8*)(Bs + jj * LSTR + kk) =
                *(const short8*)(Wt + (long)(j0 + jj) * KP + kk);
        }
    }
    __syncthreads();

    if (i0 >= N) return;

    floatx4 acc[4];
    #pragma unroll
    for (int t = 0; t < 4; ++t) { acc[t].x = 0.f; acc[t].y = 0.f; acc[t].z = 0.f; acc[t].w = 0.f; }

    const int ra = min(i0 + m, N - 1);
    const ushort_t* arow_h = F32A ? nullptr : (const ushort_t*)Xin + (long)ra * KP + quad * 8;
    const float*    arow_f = F32A ? (const float*)Xin + (long)ra * KP + quad * 8 : nullptr;

    #pragma unroll
    for (int k0 = 0; k0 < KP; k0 += 32) {
        short8 av;
        if (F32A) {
            float4 f0 = *(const float4*)(arow_f + k0);
            float4 f1 = *(const float4*)(arow_f + k0 + 4);
            av[0] = (short)f2bf(f0.x); av[1] = (short)f2bf(f0.y);
            av[2] = (short)f2bf(f0.z); av[3] = (short)f2bf(f0.w);
            av[4] = (short)f2bf(f1.x); av[5] = (short)f2bf(f1.y);
            av[6] = (short)f2bf(f1.z); av[7] = (short)f2bf(f1.w);
        } else {
            av = *(const short8*)(arow_h + k0);
        }
        #pragma unroll
        for (int t = 0; t < 4; ++t) {
            if (t < ntiles) {
                short8 bv = *(const short8*)(Bs + (t * 16 + m) * LSTR + k0 + quad * 8);
                acc[t] = __builtin_amdgcn_mfma_f32_16x16x32_bf16(av, bv, acc[t], 0, 0, 0);
            }
        }
    }

    #pragma unroll
    for (int t = 0; t < 4; ++t) {
        if (t < ntiles) {
            int j = j0 + t * 16 + m;
            float wb = wbias[j];
            #pragma unroll
            for (int r = 0; r < 4; ++r) {
                int i = i0 + quad * 4 + r;
                if (i < N) h2[(long)i * Mp + j] = f2bf((acc[t][r] + wb) * dinv[i]);
            }
        }
    }
}

// ---------------- aggregation (CSR gather, uint4 = 8 bf16/thread) ----------------
__device__ __forceinline__ void acc8(float* acc, uint4 w) {
    acc[0] += bf2f((ushort_t)(w.x & 0xffff)); acc[1] += bf2f((ushort_t)(w.x >> 16));
    acc[2] += bf2f((ushort_t)(w.y & 0xffff)); acc[3] += bf2f((ushort_t)(w.y >> 16));
    acc[4] += bf2f((ushort_t)(w.z & 0xffff)); acc[5] += bf2f((ushort_t)(w.z >> 16));
    acc[6] += bf2f((ushort_t)(w.w & 0xffff)); acc[7] += bf2f((ushort_t)(w.w >> 16));
}

__global__ __launch_bounds__(256) void k_agg(
    const int* __restrict__ row_start, const int* __restrict__ csr_src,
    const ushort_t* __restrict__ h2, int hs,
    const float* __restrict__ dinv, const float* __restrict__ b,
    ushort_t* __restrict__ tmpb, int ts,
    int N, int M, int Q, ull_t magic, uint_t sh)
{
    const uint_t g = blockIdx.x * 256 + threadIdx.x;
    const uint_t i = (uint_t)(((ull_t)g * magic) >> sh);
    const int jp = (int)(g - i * Q);
    if (i >= (uint_t)N) return;
    const int j0 = jp * 8;
    if (j0 >= M) {
        *(uint4*)(tmpb + (long)i * ts + j0) = make_uint4(0u, 0u, 0u, 0u);
        return;
    }
    const int s0 = row_start[i];
    const int s1 = row_start[i + 1];
    const ushort_t* hp = h2 + j0;
    float acc[8];
    {
        uint4 v = *(const uint4*)(hp + (long)i * hs);
        acc[0] = bf2f((ushort_t)(v.x & 0xffff)); acc[1] = bf2f((ushort_t)(v.x >> 16));
        acc[2] = bf2f((ushort_t)(v.y & 0xffff)); acc[3] = bf2f((ushort_t)(v.y >> 16));
        acc[4] = bf2f((ushort_t)(v.z & 0xffff)); acc[5] = bf2f((ushort_t)(v.z >> 16));
        acc[6] = bf2f((ushort_t)(v.w & 0xffff)); acc[7] = bf2f((ushort_t)(v.w >> 16));
    }
    int e = s0;
    for (; e + 3 < s1; e += 4) {
        int n0 = csr_src[e], n1 = csr_src[e + 1], n2 = csr_src[e + 2], n3 = csr_src[e + 3];
        uint4 w0 = *(const uint4*)(hp + (long)n0 * hs);
        uint4 w1 = *(const uint4*)(hp + (long)n1 * hs);
        uint4 w2 = *(const uint4*)(hp + (long)n2 * hs);
        uint4 w3 = *(const uint4*)(hp + (long)n3 * hs);
        acc8(acc, w0); acc8(acc, w1); acc8(acc, w2); acc8(acc, w3);
    }
    for (; e < s1; ++e) {
        uint4 w = *(const uint4*)(hp + (long)csr_src[e] * hs);
        acc8(acc, w);
    }
    const float di = dinv[i];
    ushort_t r[8];
    #pragma unroll
    for (int u = 0; u < 8; ++u) {
        float v = (j0 + u < M) ? fmaxf(acc[u] * di + b[j0 + u], 0.f) : 0.f;
        r[u] = f2bf(v);
    }
    uint4 pk;
    pk.x = (uint_t)r[0] | ((uint_t)r[1] << 16);
    pk.y = (uint_t)r[2] | ((uint_t)r[3] << 16);
    pk.z = (uint_t)r[4] | ((uint_t)r[5] << 16);
    pk.w = (uint_t)r[6] | ((uint_t)r[7] << 16);
    *(uint4*)(tmpb + (long)i * ts + j0) = pk;
}

// ---------------- BN stats: fixed-point ull atomics (order-independent => deterministic) ----------------
__global__ __launch_bounds__(256) void k_stats(
    const ushort_t* __restrict__ tmpb, int ts,
    ull_t* __restrict__ cs, ull_t* __restrict__ cq, int N)
{
    const int t = threadIdx.x;
    if (2 * t >= ts) return;
    const int i0 = blockIdx.x * 64;
    float s0 = 0.f, q0 = 0.f, s1 = 0.f, q1 = 0.f;
    for (int r = 0; r < 64; ++r) {
        int i = i0 + r;
        if (i < N) {
            uint_t w = *(const uint_t*)(tmpb + (long)i * ts + 2 * t);
            float v0 = bf2f((ushort_t)(w & 0xffff));
            float v1 = bf2f((ushort_t)(w >> 16));
            s0 += v0; q0 += v0 * v0;
            s1 += v1; q1 += v1 * v1;
        }
    }
    // post-ReLU partials are >= 0: fixed-point encode is safe in ull
    atomicAdd(&cs[2 * t],     (ull_t)llround((double)s0 * FXP));
    atomicAdd(&cq[2 * t],     (ull_t)llround((double)q0 * FXP));
    atomicAdd(&cs[2 * t + 1], (ull_t)llround((double)s1 * FXP));
    atomicAdd(&cq[2 * t + 1], (ull_t)llround((double)q1 * FXP));
}

// ---------------- final layer: gather + bias + log_softmax ----------------
__global__ __launch_bounds__(256) void k_agg_final(
    const int* __restrict__ row_start, const int* __restrict__ csr_src,
    const ushort_t* __restrict__ h2, const float* __restrict__ dinv,
    const float* __restrict__ b, float* __restrict__ out, int N, int M)
{
    const int x = threadIdx.x;                 // 0..15
    const int i = blockIdx.x * 16 + threadIdx.y;
    if (i >= N) return;
    const int j0 = 2 * x, j1 = 2 * x + 1;
    uint_t v = *(const uint_t*)(h2 + (long)i * 32 + j0);
    float a0 = bf2f((ushort_t)(v & 0xffff));
    float a1 = bf2f((ushort_t)(v >> 16));
    const int s0 = row_start[i];
    const int s1 = row_start[i + 1];
    int e = s0;
    for (; e + 1 < s1; e += 2) {
        int n0 = csr_src[e], n1 = csr_src[e + 1];
        uint_t w0 = *(const uint_t*)(h2 + (long)n0 * 32 + j0);
        uint_t w1 = *(const uint_t*)(h2 + (long)n1 * 32 + j0);
        a0 += bf2f((ushort_t)(w0 & 0xffff)); a1 += bf2f((ushort_t)(w0 >> 16));
        a0 += bf2f((ushort_t)(w1 & 0xffff)); a1 += bf2f((ushort_t)(w1 >> 16));
    }
    for (; e < s1; ++e) {
        uint_t w = *(const uint_t*)(h2 + (long)csr_src[e] * 32 + j0);
        a0 += bf2f((ushort_t)(w & 0xffff)); a1 += bf2f((ushort_t)(w >> 16));
    }
    const float di = dinv[i];
    float r0 = (j0 < M) ? (a0 * di + b[j0]) : -INFINITY;
    float r1 = (j1 < M) ? (a1 * di + b[j1]) : -INFINITY;
    float m = fmaxf(r0, r1);
    #pragma unroll
    for (int msk = 1; msk < 16; msk <<= 1) m = fmaxf(m, __shfl_xor(m, msk, 16));
    float s = ((j0 < M) ? expf(r0 - m) : 0.f) + ((j1 < M) ? expf(r1 - m) : 0.f);
    #pragma unroll
    for (int msk = 1; msk < 16; msk <<= 1) s += __shfl_xor(s, msk, 16);
    const float l = logf(s) + m;
    if (j0 < M) out[(long)i * M + j0] = r0 - l;
    if (j1 < M) out[(long)i * M + j1] = r1 - l;
}

// ---------------- launch ----------------

static inline int pad16(int v) { return (v + 15) & ~15; }
static inline int pad32(int v) { return (v + 31) & ~31; }

extern "C" void kernel_launch(void* const* d_in, const int* in_sizes, int n_in,
                              void* d_out, int out_size, void* d_ws, size_t ws_size,
                              hipStream_t stream)
{
    const int dims[6] = {256, 220, 150, 100, 60, 17};
    const int N = in_sizes[0] / dims[0];      // 10000
    const int E = in_sizes[1] / 2;            // 320000

    const float* x  = (const float*)d_in[0];
    const int* ei   = (const int*)d_in[1];
    const int* srcv = ei;
    const int* dstv = ei + E;
    const float* Wl[5], *bl[5];
    for (int l = 0; l < 5; ++l) {
        Wl[l] = (const float*)d_in[2 + 2 * l];
        bl[l] = (const float*)d_in[3 + 2 * l];
    }
    const float* gl[4], *bel[4];
    for (int l = 0; l < 4; ++l) {
        gl[l]  = (const float*)d_in[12 + 2 * l];
        bel[l] = (const float*)d_in[13 + 2 * l];
    }
    float* out = (float*)d_out;

    // ---- workspace layout ----
    char* w = (char*)d_ws;
    const long NB  = ((long)N * 4 + 255) & ~255L;
    const long NB1 = ((long)(N + 1) * 4 + 255) & ~255L;
    const long EB  = ((long)E * 4 + 255) & ~255L;
    const long FBB = ((long)N * 224 * 2 + 255) & ~255L;
    const long WTB = ((long)224 * 256 * 2 + 255) & ~255L;

    long o = 0;
    float* dinv      = (float*)(w + o);  o += NB;
    ull_t* stats     = (ull_t*)(w + o);  o += 2048 * 8;   // 4 layers x (cs[256]+cq[256]) ull
    float* wbias     = (float*)(w + o);  o += 1024;
    int*   cnt       = (int*)(w + o);    o += NB;
    int*   row_start = (int*)(w + o);    o += NB1;
    int*   cursor    = (int*)(w + o);    o += NB;
    int*   csr_src   = (int*)(w + o);    o += EB;
    ushort_t* Wt     = (ushort_t*)(w + o); o += WTB;
    ushort_t* h2     = (ushort_t*)(w + o); o += FBB;
    ushort_t* tmpb   = (ushort_t*)(w + o); o += FBB;

    const float invN = 1.0f / (float)N;

    k_init<<<224, 256, 0, stream>>>(Wl[0], cnt, stats, wbias, Wt, N);
    k_hist<<<(E + 255) / 256, 256, 0, stream>>>(dstv, cnt, E);
    k_scan<<<1, 1024, 0, stream>>>(cnt, row_start, cursor, dinv, N);
    k_fill<<<(E + 255) / 256, 256, 0, stream>>>(srcv, dstv, cursor, csr_src, E);
    k_sort<<<N, 64, 0, stream>>>(row_start, csr_src, N);

    for (int l = 0; l < 5; ++l) {
        const int K  = dims[l];
        const int M  = dims[l + 1];
        const int Kp = pad32(K);
        const int Mp = pad16(M);
        const int ts = (l < 4) ? pad32(M) : 32;

        if (l > 0) {
            const int yW = (Mp + 3) / 4;
            k_prep<<<dim3((Kp + 63) / 64, yW + 1), dim3(64, 4), 0, stream>>>(
                Wl[l], gl[l - 1], bel[l - 1],
                stats + (l - 1) * 512, stats + (l - 1) * 512 + 256,
                Wt, wbias, K, M, Kp, Mp, yW, invN);
        }

        dim3 gg((N + 63) / 64, (Mp + 63) / 64);
        if (l == 0) {
            k_gemm_mfma<256, true><<<gg, 256, 0, stream>>>(x, Wt, wbias, dinv, h2, N, Mp);
        } else {
            switch (Kp) {
                case 224: k_gemm_mfma<224, false><<<gg, 256, 0, stream>>>(tmpb, Wt, wbias, dinv, h2, N, Mp); break;
                case 160: k_gemm_mfma<160, false><<<gg, 256, 0, stream>>>(tmpb, Wt, wbias, dinv, h2, N, Mp); break;
                case 128: k_gemm_mfma<128, false><<<gg, 256, 0, stream>>>(tmpb, Wt, wbias, dinv, h2, N, Mp); break;
                case  64: k_gemm_mfma< 64, false><<<gg, 256, 0, stream>>>(tmpb, Wt, wbias, dinv, h2, N, Mp); break;
            }
        }

        if (l < 4) {
            const int Q = ts / 8;
            uint_t shmt = 0;
            while ((1u << shmt) < (uint_t)Q) ++shmt;
            shmt += 32;
            const ull_t magic = ((1ULL << shmt) + Q - 1) / (ull_t)Q;   // 64-bit (pow2 Q!)
            const long total = (long)N * Q;
            k_agg<<<(int)((total + 255) / 256), 256, 0, stream>>>(
                row_start, csr_src, h2, Mp, dinv, bl[l], tmpb, ts, N, M, Q, magic, shmt);
            k_stats<<<(N + 63) / 64, 256, 0, stream>>>(tmpb, ts,
                stats + l * 512, stats + l * 512 + 256, N);
        } else {
            k_agg_final<<<(N + 15) / 16, dim3(16, 16), 0, stream>>>(
                row_start, csr_src, h2, dinv, bl[l], out, N, M);
        }
    }
}